// Round 3
// baseline (2691.064 us; speedup 1.0000x reference)
//
#include <hip/hip_runtime.h>

#define E 1024
#define KK 20
#define NOUT 40980      // KK*(2*E+1)
#define VLOC 20500      // KK + KK*E
#define SROW (2*NOUT)   // 81960
#define NPAIR 190       // K*(K-1)/2
#define GOFF 8
#define GS 784          // per-(b,which) gram slot stride (floats)
#define FCH 256         // f per LDS chunk in main
#define NCH (E/FCH)

// ws floats: [0]=sumT2(den) [1]=S2 [2]=objU [3]=objV [4]=S3
// [GOFF + (b*2+which)*GS): [0..380) no-conj pairs (re,im) | [380..760) conj pairs | [760..780) conj diag

__global__ void init_ws_kernel(float* ws, int n) {
    int i = blockIdx.x * blockDim.x + threadIdx.x;
    if (i < n) ws[i] = 0.0f;
}

// ---- Gram partials: 512 blocks = B*2*8 e-chunks of 128. no-conj (obj) + conj (|P|^2) ----
__global__ __launch_bounds__(256) void gram_kernel(const float* __restrict__ nn,
                                                   float* __restrict__ ws) {
    const int CH = 128;
    __shared__ float2 sM[CH * 21];
    int bx = blockIdx.x;
    int chunk = bx & 7, which = (bx >> 3) & 1, b = bx >> 4;
    const float* baseR = nn + (size_t)b * SROW + (which ? VLOC : KK) + chunk * CH * KK;
    const float* baseI = baseR + NOUT;
    int t = threadIdx.x;
    for (int idx = t; idx < CH * KK; idx += 256) {
        int dst = idx + idx / KK;           // pad 20 -> 21 float2
        sM[dst] = make_float2(baseR[idx], baseI[idx]);
    }
    __syncthreads();
    float* g = ws + GOFF + (size_t)(b * 2 + which) * GS;
    if (t < NPAIR) {
        int p = t, j = 0, cnt = KK - 1;
        while (p >= cnt) { p -= cnt; j++; cnt--; }
        int kq = j + 1 + p;
        float gr = 0.f, gi = 0.f, cr = 0.f, ci = 0.f;
        #pragma unroll 4
        for (int e = 0; e < CH; e++) {
            float2 a = sM[e * 21 + j];
            float2 c = sM[e * 21 + kq];
            gr += a.x * c.x - a.y * c.y;   // a*c
            gi += a.x * c.y + a.y * c.x;
            cr += a.x * c.x + a.y * c.y;   // a*conj(c)
            ci += a.y * c.x - a.x * c.y;
        }
        atomicAdd(&g[2 * t], gr);       atomicAdd(&g[2 * t + 1], gi);
        atomicAdd(&g[380 + 2 * t], cr); atomicAdd(&g[380 + 2 * t + 1], ci);
    } else if (t < NPAIR + KK) {
        int k = t - NPAIR;
        float s = 0.f;
        #pragma unroll 4
        for (int e = 0; e < CH; e++) { float2 a = sM[e * 21 + k]; s += a.x * a.x + a.y * a.y; }
        atomicAdd(&g[760 + k], s);
    }
}

// ---- main: stream T once. grid (64 e-groups, B). wave = 4 e-rows, lane = 4 f per chunk ----
__global__ __launch_bounds__(256, 2) void main_kernel(const float* __restrict__ nn,
                                                      const float* __restrict__ kr,
                                                      const float* __restrict__ ki,
                                                      float* __restrict__ ws) {
    __shared__ __align__(16) float2 sV[KK * FCH];   // [k][f_local], conflict-free both sides
    int b = blockIdx.y;
    int t = threadIdx.x;
    int w = t >> 6, L = t & 63;
    int ebase = blockIdx.x * 16 + w * 4;
    const float* nb = nn + (size_t)b * SROW;
    const float* vR = nb + VLOC;
    const float* vI = vR + NOUT;
    const float* TR = kr + ((size_t)b * E + ebase) * E;
    const float* TI = ki + ((size_t)b * E + ebase) * E;

    float ar[4][KK], ai[4][KK];
    #pragma unroll
    for (int e = 0; e < 4; e++)
        #pragma unroll
        for (int k = 0; k < KK; k++) { ar[e][k] = 0.f; ai[e][k] = 0.f; }
    float t2 = 0.f;

    for (int c = 0; c < NCH; c++) {
        int f0 = c * FCH;
        __syncthreads();
        // stage V chunk transposed [k][f]: per-wave k uniform, lanes write consecutive b128
        #pragma unroll
        for (int m = 0; m < 10; m++) {
            int flat = t + 256 * m;         // 0..2559 = 20k x 128 f-pairs
            int k = flat >> 7;              // wave-uniform
            int fp = flat & 127;
            int f = f0 + 2 * fp;
            float r0 = vR[(size_t)f * KK + k];
            float i0 = vI[(size_t)f * KK + k];
            float r1 = vR[(size_t)(f + 1) * KK + k];
            float i1 = vI[(size_t)(f + 1) * KK + k];
            *(float4*)&sV[k * FCH + 2 * fp] = make_float4(r0, i0, r1, i1);
        }
        __syncthreads();
        #pragma unroll
        for (int h = 0; h < 2; h++) {       // 2 f-pairs per lane per chunk
            int fo = f0 + 4 * L + 2 * h;
            float2 tr2[4], ti2[4];
            #pragma unroll
            for (int e = 0; e < 4; e++) {
                tr2[e] = *(const float2*)(TR + (size_t)e * E + fo);
                ti2[e] = *(const float2*)(TI + (size_t)e * E + fo);
            }
            #pragma unroll
            for (int e = 0; e < 4; e++)
                t2 += tr2[e].x * tr2[e].x + tr2[e].y * tr2[e].y
                    + ti2[e].x * ti2[e].x + ti2[e].y * ti2[e].y;
            #pragma unroll
            for (int k = 0; k < KK; k++) {
                float4 v = *(const float4*)&sV[k * FCH + 4 * L + 2 * h];  // (vr0,vi0,vr1,vi1)
                #pragma unroll
                for (int e = 0; e < 4; e++) {
                    // Ybar += conj(T)*V
                    ar[e][k] += tr2[e].x * v.x + ti2[e].x * v.y;
                    ai[e][k] += tr2[e].x * v.y - ti2[e].x * v.x;
                    ar[e][k] += tr2[e].y * v.z + ti2[e].y * v.w;
                    ai[e][k] += tr2[e].y * v.w - ti2[e].y * v.z;
                }
            }
        }
    }

    // S2 partial: Re sum_{e,k} W[e,k]*Ybar[e,k], W = U*d  (wave-uniform broadcast loads)
    float s2 = 0.f;
    #pragma unroll
    for (int k = 0; k < KK; k++) {
        float dr = nb[k], di = nb[NOUT + k];
        #pragma unroll
        for (int e = 0; e < 4; e++) {
            float ur = nb[KK + (size_t)(ebase + e) * KK + k];
            float ui = nb[NOUT + KK + (size_t)(ebase + e) * KK + k];
            float wr = ur * dr - ui * di;
            float wi = ur * di + ui * dr;
            s2 += wr * ar[e][k] - wi * ai[e][k];
        }
    }
    #pragma unroll
    for (int off = 32; off > 0; off >>= 1) {
        t2 += __shfl_down(t2, off, 64);
        s2 += __shfl_down(s2, off, 64);
    }
    if (L == 0) { atomicAdd(&ws[0], t2); atomicAdd(&ws[1], s2); }
}

// ---- fin2: per-b combine Grams -> objU, objV, S3. 32 blocks ----
__global__ __launch_bounds__(256) void fin2_kernel(const float* __restrict__ nn,
                                                   float* __restrict__ ws) {
    __shared__ float red[3][4];
    int b = blockIdx.x;
    int t = threadIdx.x;
    const float* nb = nn + (size_t)b * SROW;
    const float* gu = ws + GOFF + (size_t)(b * 2 + 0) * GS;
    const float* gv = ws + GOFF + (size_t)(b * 2 + 1) * GS;
    float oU = 0.f, oV = 0.f, s3 = 0.f;
    if (t < NPAIR) {
        int p = t, j = 0, cnt = KK - 1;
        while (p >= cnt) { p -= cnt; j++; cnt--; }
        int kq = j + 1 + p;
        float gr = gu[2 * t], gi = gu[2 * t + 1];
        oU = sqrtf(gr * gr + gi * gi);
        float hr = gv[2 * t], hi = gv[2 * t + 1];
        oV = sqrtf(hr * hr + hi * hi);
        // GwC = d[j]*conj(d[kq])*GuC ; s3 pair term = 2*Re(GwC*GvC)
        float djr = nb[j], dji = nb[NOUT + j], dkr = nb[kq], dki = nb[NOUT + kq];
        float pr = djr * dkr + dji * dki;
        float pi = dji * dkr - djr * dki;
        float ur = gu[380 + 2 * t], ui = gu[380 + 2 * t + 1];
        float wr = pr * ur - pi * ui;
        float wi = pr * ui + pi * ur;
        float vr = gv[380 + 2 * t], vi = gv[380 + 2 * t + 1];
        s3 = 2.f * (wr * vr - wi * vi);
    } else if (t < NPAIR + KK) {
        int k = t - NPAIR;
        float dr = nb[k], di = nb[NOUT + k];
        s3 = (dr * dr + di * di) * gu[760 + k] * gv[760 + k];
    }
    #pragma unroll
    for (int off = 32; off > 0; off >>= 1) {
        oU += __shfl_down(oU, off, 64);
        oV += __shfl_down(oV, off, 64);
        s3 += __shfl_down(s3, off, 64);
    }
    int w = t >> 6, L = t & 63;
    if (L == 0) { red[0][w] = oU; red[1][w] = oV; red[2][w] = s3; }
    __syncthreads();
    if (t == 0) {
        atomicAdd(&ws[2], red[0][0] + red[0][1] + red[0][2] + red[0][3]);
        atomicAdd(&ws[3], red[1][0] + red[1][1] + red[1][2] + red[1][3]);
        atomicAdd(&ws[4], red[2][0] + red[2][1] + red[2][2] + red[2][3]);
    }
}

__global__ void fin3_kernel(const float* __restrict__ ws, const int* __restrict__ bsz,
                            float* __restrict__ out) {
    if (threadIdx.x == 0 && blockIdx.x == 0) {
        float Bf = (float)bsz[0];
        float den = ws[0];
        float num = ws[0] - 2.f * ws[1] + ws[4];
        float o1 = ws[2] / Bf, o2 = ws[3] / Bf;
        out[0] = num / den + 0.01f * (o1 + o2);
        out[1] = o1;
        out[2] = o2;
    }
}

extern "C" void kernel_launch(void* const* d_in, const int* in_sizes, int n_in,
                              void* d_out, int out_size, void* d_ws, size_t ws_size,
                              hipStream_t stream) {
    const float* nn = (const float*)d_in[0];
    const float* kr = (const float*)d_in[1];
    const float* ki = (const float*)d_in[2];
    const int* bsz = (const int*)d_in[3];
    float* ws = (float*)d_ws;
    float* out = (float*)d_out;
    int B = in_sizes[0] / SROW;

    int nz = GOFF + B * 2 * GS;
    hipLaunchKernelGGL(init_ws_kernel, dim3((nz + 255) / 256), dim3(256), 0, stream, ws, nz);
    hipLaunchKernelGGL(gram_kernel, dim3(B * 2 * 8), dim3(256), 0, stream, nn, ws);
    hipLaunchKernelGGL(main_kernel, dim3(E / 16, B), dim3(256), 0, stream, nn, kr, ki, ws);
    hipLaunchKernelGGL(fin2_kernel, dim3(B), dim3(256), 0, stream, nn, ws);
    hipLaunchKernelGGL(fin3_kernel, dim3(1), dim3(64), 0, stream, ws, bsz, out);
}

// Round 4
// 651.802 us; speedup vs baseline: 4.1287x; 4.1287x over previous
//
#include <hip/hip_runtime.h>

#define E 1024
#define KK 20
#define NOUT 40980      // KK*(2*E+1)
#define VLOC 20500      // KK + KK*E
#define SROW (2*NOUT)   // 81960
#define NPAIR 190       // K*(K-1)/2
#define GOFF 8
#define GS 784          // per-(b,which) gram slot stride (floats)
#define FCH 256         // f per LDS chunk in main
#define VPAD 21         // float2 stride per f-row in sV

// ws floats: [0]=sumT2(den) [1]=S2 [2]=objU [3]=objV [4]=S3
// [GOFF + (b*2+which)*GS): [0..380) no-conj pairs | [380..760) conj pairs | [760..780) conj diag

__global__ void init_ws_kernel(float* ws, int n) {
    int i = blockIdx.x * blockDim.x + threadIdx.x;
    if (i < n) ws[i] = 0.0f;
}

// ---- Gram partials: 512 blocks = B*2*8 e-chunks of 128 ----
__global__ __launch_bounds__(256) void gram_kernel(const float* __restrict__ nn,
                                                   float* __restrict__ ws) {
    const int CH = 128;
    __shared__ float2 sM[CH * 21];
    int bx = blockIdx.x;
    int chunk = bx & 7, which = (bx >> 3) & 1, b = bx >> 4;
    const float* baseR = nn + (size_t)b * SROW + (which ? VLOC : KK) + chunk * CH * KK;
    const float* baseI = baseR + NOUT;
    int t = threadIdx.x;
    for (int idx = t; idx < CH * KK; idx += 256) {
        int dst = idx + idx / KK;           // pad 20 -> 21 float2
        sM[dst] = make_float2(baseR[idx], baseI[idx]);
    }
    __syncthreads();
    float* g = ws + GOFF + (size_t)(b * 2 + which) * GS;
    if (t < NPAIR) {
        int p = t, j = 0, cnt = KK - 1;
        while (p >= cnt) { p -= cnt; j++; cnt--; }
        int kq = j + 1 + p;
        float gr = 0.f, gi = 0.f, cr = 0.f, ci = 0.f;
        #pragma unroll 4
        for (int e = 0; e < CH; e++) {
            float2 a = sM[e * 21 + j];
            float2 c = sM[e * 21 + kq];
            gr += a.x * c.x - a.y * c.y;   // a*c
            gi += a.x * c.y + a.y * c.x;
            cr += a.x * c.x + a.y * c.y;   // a*conj(c)
            ci += a.y * c.x - a.x * c.y;
        }
        atomicAdd(&g[2 * t], gr);       atomicAdd(&g[2 * t + 1], gi);
        atomicAdd(&g[380 + 2 * t], cr); atomicAdd(&g[380 + 2 * t + 1], ci);
    } else if (t < NPAIR + KK) {
        int k = t - NPAIR;
        float s = 0.f;
        #pragma unroll 4
        for (int e = 0; e < CH; e++) { float2 a = sM[e * 21 + k]; s += a.x * a.x + a.y * a.y; }
        atomicAdd(&g[760 + k], s);
    }
}

// ---- main: stream T once. grid (E/16, B). wave: 4 e-rows; lane=(fg,kg): 5-k split ----
// Per-lane accum Ybar[4e][5k] complex = 40 VGPRs (no spill). kg-duplicate T reads are
// same-address within the wave -> dedup'd, T HBM traffic = 268 MB exactly once.
__global__ __launch_bounds__(256) void main_kernel(const float* __restrict__ nn,
                                                   const float* __restrict__ kr,
                                                   const float* __restrict__ ki,
                                                   float* __restrict__ ws) {
    __shared__ __align__(16) float2 sV[FCH * VPAD];   // [f_local][k], f-stride 21
    int b = blockIdx.y;
    int t = threadIdx.x;
    int w = t >> 6, L = t & 63;
    int fg = L & 15, kg = L >> 4;
    int ebase = blockIdx.x * 16 + w * 4;
    const float* nb = nn + (size_t)b * SROW;
    const float* vR = nb + VLOC;
    const float* vI = vR + NOUT;
    const float* TR = kr + ((size_t)b * E + ebase) * E;
    const float* TI = ki + ((size_t)b * E + ebase) * E;

    float ar[4][5], ai[4][5];
    #pragma unroll
    for (int e = 0; e < 4; e++)
        #pragma unroll
        for (int kj = 0; kj < 5; kj++) { ar[e][kj] = 0.f; ai[e][kj] = 0.f; }
    float t2 = 0.f;

    for (int c = 0; c < E / FCH; c++) {
        int f0 = c * FCH;
        __syncthreads();
        // stage V chunk: thread t owns f-row t; 5 float4 from each of vR, vI; interleave
        {
            const float* r = vR + (size_t)(f0 + t) * KK;
            const float* im = vI + (size_t)(f0 + t) * KK;
            float2* dst = &sV[t * VPAD];
            #pragma unroll
            for (int m = 0; m < 5; m++) {
                float4 a = *(const float4*)(r + 4 * m);
                float4 bb = *(const float4*)(im + 4 * m);
                dst[4 * m + 0] = make_float2(a.x, bb.x);
                dst[4 * m + 1] = make_float2(a.y, bb.y);
                dst[4 * m + 2] = make_float2(a.z, bb.z);
                dst[4 * m + 3] = make_float2(a.w, bb.w);
            }
        }
        __syncthreads();
        #pragma unroll
        for (int q = 0; q < 4; q++) {
            int fl = (q * 16 + fg) * 4;        // local f base of this lane's quad
            int fgl = f0 + fl;                 // global f
            float4 tr4[4], ti4[4];
            #pragma unroll
            for (int e = 0; e < 4; e++) {
                tr4[e] = *(const float4*)(TR + (size_t)e * E + fgl);
                ti4[e] = *(const float4*)(TI + (size_t)e * E + fgl);
            }
            #pragma unroll
            for (int e = 0; e < 4; e++) {
                t2 += tr4[e].x * tr4[e].x + tr4[e].y * tr4[e].y
                    + tr4[e].z * tr4[e].z + tr4[e].w * tr4[e].w;
                t2 += ti4[e].x * ti4[e].x + ti4[e].y * ti4[e].y
                    + ti4[e].z * ti4[e].z + ti4[e].w * ti4[e].w;
            }
            #pragma unroll
            for (int fi = 0; fi < 4; fi++) {
                #pragma unroll
                for (int kj = 0; kj < 5; kj++) {
                    float2 v = sV[(fl + fi) * VPAD + kg * 5 + kj];
                    #pragma unroll
                    for (int e = 0; e < 4; e++) {
                        float trx = ((const float*)&tr4[e])[fi];
                        float tix = ((const float*)&ti4[e])[fi];
                        // Ybar += conj(T)*V
                        ar[e][kj] += trx * v.x + tix * v.y;
                        ai[e][kj] += trx * v.y - tix * v.x;
                    }
                }
            }
        }
    }

    // s2 partial: Re sum W[e,k]*Ybar[e,k] over this lane's (4e, 5k)
    float s2 = 0.f;
    #pragma unroll
    for (int kj = 0; kj < 5; kj++) {
        int k = kg * 5 + kj;
        float dr = nb[k], di = nb[NOUT + k];
        #pragma unroll
        for (int e = 0; e < 4; e++) {
            float ur = nb[KK + (size_t)(ebase + e) * KK + k];
            float ui = nb[NOUT + KK + (size_t)(ebase + e) * KK + k];
            float wr = ur * dr - ui * di;
            float wi = ur * di + ui * dr;
            s2 += wr * ar[e][kj] - wi * ai[e][kj];
        }
    }
    t2 *= 0.25f;   // kg 4-way duplication of T reads
    #pragma unroll
    for (int off = 32; off > 0; off >>= 1) {
        t2 += __shfl_down(t2, off, 64);
        s2 += __shfl_down(s2, off, 64);
    }
    if (L == 0) { atomicAdd(&ws[0], t2); atomicAdd(&ws[1], s2); }
}

// ---- fin2: per-b combine Grams -> objU, objV, S3 ----
__global__ __launch_bounds__(256) void fin2_kernel(const float* __restrict__ nn,
                                                   float* __restrict__ ws) {
    __shared__ float red[3][4];
    int b = blockIdx.x;
    int t = threadIdx.x;
    const float* nb = nn + (size_t)b * SROW;
    const float* gu = ws + GOFF + (size_t)(b * 2 + 0) * GS;
    const float* gv = ws + GOFF + (size_t)(b * 2 + 1) * GS;
    float oU = 0.f, oV = 0.f, s3 = 0.f;
    if (t < NPAIR) {
        int p = t, j = 0, cnt = KK - 1;
        while (p >= cnt) { p -= cnt; j++; cnt--; }
        int kq = j + 1 + p;
        float gr = gu[2 * t], gi = gu[2 * t + 1];
        oU = sqrtf(gr * gr + gi * gi);
        float hr = gv[2 * t], hi = gv[2 * t + 1];
        oV = sqrtf(hr * hr + hi * hi);
        float djr = nb[j], dji = nb[NOUT + j], dkr = nb[kq], dki = nb[NOUT + kq];
        float pr = djr * dkr + dji * dki;     // d_j * conj(d_k)
        float pi = dji * dkr - djr * dki;
        float ur = gu[380 + 2 * t], ui = gu[380 + 2 * t + 1];
        float wr = pr * ur - pi * ui;
        float wi = pr * ui + pi * ur;
        float vr = gv[380 + 2 * t], vi = gv[380 + 2 * t + 1];
        s3 = 2.f * (wr * vr - wi * vi);
    } else if (t < NPAIR + KK) {
        int k = t - NPAIR;
        float dr = nb[k], di = nb[NOUT + k];
        s3 = (dr * dr + di * di) * gu[760 + k] * gv[760 + k];
    }
    #pragma unroll
    for (int off = 32; off > 0; off >>= 1) {
        oU += __shfl_down(oU, off, 64);
        oV += __shfl_down(oV, off, 64);
        s3 += __shfl_down(s3, off, 64);
    }
    int w = t >> 6, L = t & 63;
    if (L == 0) { red[0][w] = oU; red[1][w] = oV; red[2][w] = s3; }
    __syncthreads();
    if (t == 0) {
        atomicAdd(&ws[2], red[0][0] + red[0][1] + red[0][2] + red[0][3]);
        atomicAdd(&ws[3], red[1][0] + red[1][1] + red[1][2] + red[1][3]);
        atomicAdd(&ws[4], red[2][0] + red[2][1] + red[2][2] + red[2][3]);
    }
}

__global__ void fin3_kernel(const float* __restrict__ ws, const int* __restrict__ bsz,
                            float* __restrict__ out) {
    if (threadIdx.x == 0 && blockIdx.x == 0) {
        float Bf = (float)bsz[0];
        float den = ws[0];
        float num = ws[0] - 2.f * ws[1] + ws[4];
        float o1 = ws[2] / Bf, o2 = ws[3] / Bf;
        out[0] = num / den + 0.01f * (o1 + o2);
        out[1] = o1;
        out[2] = o2;
    }
}

extern "C" void kernel_launch(void* const* d_in, const int* in_sizes, int n_in,
                              void* d_out, int out_size, void* d_ws, size_t ws_size,
                              hipStream_t stream) {
    const float* nn = (const float*)d_in[0];
    const float* kr = (const float*)d_in[1];
    const float* ki = (const float*)d_in[2];
    const int* bsz = (const int*)d_in[3];
    float* ws = (float*)d_ws;
    float* out = (float*)d_out;
    int B = in_sizes[0] / SROW;

    int nz = GOFF + B * 2 * GS;
    hipLaunchKernelGGL(init_ws_kernel, dim3((nz + 255) / 256), dim3(256), 0, stream, ws, nz);
    hipLaunchKernelGGL(gram_kernel, dim3(B * 2 * 8), dim3(256), 0, stream, nn, ws);
    hipLaunchKernelGGL(main_kernel, dim3(E / 16, B), dim3(256), 0, stream, nn, kr, ki, ws);
    hipLaunchKernelGGL(fin2_kernel, dim3(B), dim3(256), 0, stream, nn, ws);
    hipLaunchKernelGGL(fin3_kernel, dim3(1), dim3(64), 0, stream, ws, bsz, out);
}

// Round 5
// 442.031 us; speedup vs baseline: 6.0880x; 1.4746x over previous
//
#include <hip/hip_runtime.h>

#define E 1024
#define KK 20
#define NOUT 40980      // KK*(2*E+1)
#define VLOC 20500      // KK + KK*E
#define SROW (2*NOUT)   // 81960
#define NPAIR 190       // K*(K-1)/2
#define GOFF 8
#define GS 380          // per-(b,which) gram slot stride (floats): 190 pairs * (re,im)
#define SWS 66          // float2 stride per k-row in sW/sV (64 + 2 pad)

// ws floats: [0]=num [1]=den [2]=objU [3]=objV ; [GOFF + (b*2+which)*GS) gram pairs

__global__ void init_ws_kernel(float* ws, int n) {
    int i = blockIdx.x * blockDim.x + threadIdx.x;
    if (i < n) ws[i] = 0.0f;
}

// ---- Gram partials (obj penalty): 512 blocks = B*2*8 e-chunks of 128 ----
__global__ __launch_bounds__(256) void gram_kernel(const float* __restrict__ nn,
                                                   float* __restrict__ ws) {
    const int CH = 128;
    __shared__ float2 sM[CH * 21];
    int bx = blockIdx.x;
    int chunk = bx & 7, which = (bx >> 3) & 1, b = bx >> 4;
    const float* baseR = nn + (size_t)b * SROW + (which ? VLOC : KK) + chunk * CH * KK;
    const float* baseI = baseR + NOUT;
    int t = threadIdx.x;
    for (int idx = t; idx < CH * KK; idx += 256) {
        int dst = idx + idx / KK;           // pad 20 -> 21 float2
        sM[dst] = make_float2(baseR[idx], baseI[idx]);
    }
    __syncthreads();
    float* g = ws + GOFF + (size_t)(b * 2 + which) * GS;
    if (t < NPAIR) {
        int p = t, j = 0, cnt = KK - 1;
        while (p >= cnt) { p -= cnt; j++; cnt--; }
        int kq = j + 1 + p;
        float gr = 0.f, gi = 0.f;
        #pragma unroll 4
        for (int e = 0; e < CH; e++) {
            float2 a = sM[e * 21 + j];
            float2 c = sM[e * 21 + kq];
            gr += a.x * c.x - a.y * c.y;   // a*c (no conj)
            gi += a.x * c.y + a.y * c.x;
        }
        atomicAdd(&g[2 * t], gr);
        atomicAdd(&g[2 * t + 1], gi);
    }
}

// ---- abs + reduce: B*2 blocks ----
__global__ __launch_bounds__(256) void absred_kernel(float* __restrict__ ws) {
    __shared__ float red[4];
    int bw = blockIdx.x;
    int t = threadIdx.x;
    float m = 0.f;
    if (t < NPAIR) {
        const float* g = ws + GOFF + (size_t)bw * GS;
        float gr = g[2 * t], gi = g[2 * t + 1];
        m = sqrtf(gr * gr + gi * gi);
    }
    #pragma unroll
    for (int off = 32; off > 0; off >>= 1) m += __shfl_down(m, off, 64);
    if ((t & 63) == 0) red[t >> 6] = m;
    __syncthreads();
    if (t == 0) atomicAdd(&ws[2 + (bw & 1)], red[0] + red[1] + red[2] + red[3]);
}

// ---- main: direct |T - P|^2. grid (16,16,B) = 64x64 tiles; lane = 4e x 4f ----
// sW/sV in [k][row] layout: W reads broadcast across 16 lanes, V reads 16
// consecutive float4s -> both conflict-free. T prefetched (32 VGPR), accum = 32.
__global__ __launch_bounds__(256, 3) void main_kernel(const float* __restrict__ nn,
                                                      const float* __restrict__ kr,
                                                      const float* __restrict__ ki,
                                                      float* __restrict__ ws) {
    __shared__ __align__(16) float2 sW[KK * SWS];   // [k][e_local]
    __shared__ __align__(16) float2 sV[KK * SWS];   // [k][f_local]
    __shared__ float redN[4], redD[4];
    int b = blockIdx.z;
    int e0 = blockIdx.y * 64;
    int f0 = blockIdx.x * 64;
    const float* nb = nn + (size_t)b * SROW;
    int t = threadIdx.x;
    int w = t >> 6, L = t & 63;
    int eg = L >> 4, fg = L & 15;
    int eb = w * 16 + eg * 4;      // local e base (4 rows)
    int fb = fg * 4;               // local f base (4 cols)

    // ---- prefetch T tile fragment (consumed only in epilogue; hidden by k-loop) ----
    size_t tbase = ((size_t)b * E + (size_t)(e0 + eb)) * E + (size_t)(f0 + fb);
    float4 trp[4], tip[4];
    #pragma unroll
    for (int e = 0; e < 4; e++) {
        trp[e] = *(const float4*)(kr + tbase + (size_t)e * E);
        tip[e] = *(const float4*)(ki + tbase + (size_t)e * E);
    }

    // ---- stage W = U*d and V, [k][row], wave-uniform k, lane-consecutive rows ----
    for (int idx = t; idx < 64 * KK; idx += 256) {
        int e = idx & 63, k = idx >> 6;
        float dr = nb[k], di = nb[NOUT + k];
        float ur = nb[KK + (size_t)(e0 + e) * KK + k];
        float ui = nb[NOUT + KK + (size_t)(e0 + e) * KK + k];
        float vr = nb[VLOC + (size_t)(f0 + e) * KK + k];
        float vi = nb[NOUT + VLOC + (size_t)(f0 + e) * KK + k];
        sW[k * SWS + e] = make_float2(ur * dr - ui * di, ur * di + ui * dr);
        sV[k * SWS + e] = make_float2(vr, vi);
    }
    __syncthreads();

    // ---- P accumulation: 4x4 complex per lane ----
    float pr[4][4] = {{0.f}}, pi[4][4] = {{0.f}};
    const float2* wrow = &sW[eb];
    const float2* vrow = &sV[fb];
    #pragma unroll 4
    for (int k = 0; k < KK; k++) {
        float4 wa = *(const float4*)(wrow);       // e: eb, eb+1   (broadcast x16)
        float4 wb = *(const float4*)(wrow + 2);   // e: eb+2, eb+3
        float4 va = *(const float4*)(vrow);       // f: fb, fb+1   (consecutive)
        float4 vb = *(const float4*)(vrow + 2);   // f: fb+2, fb+3
        wrow += SWS; vrow += SWS;
        float wr[4] = {wa.x, wa.z, wb.x, wb.z};
        float wi[4] = {wa.y, wa.w, wb.y, wb.w};
        float vr[4] = {va.x, va.z, vb.x, vb.z};
        float vi[4] = {va.y, va.w, vb.y, vb.w};
        #pragma unroll
        for (int e = 0; e < 4; e++)
            #pragma unroll
            for (int f = 0; f < 4; f++) {
                pr[e][f] += wr[e] * vr[f] - wi[e] * vi[f];
                pi[e][f] += wr[e] * vi[f] + wi[e] * vr[f];
            }
    }

    // ---- compare with prefetched T ----
    float num = 0.f, den = 0.f;
    #pragma unroll
    for (int e = 0; e < 4; e++) {
        float tr4[4] = {trp[e].x, trp[e].y, trp[e].z, trp[e].w};
        float ti4[4] = {tip[e].x, tip[e].y, tip[e].z, tip[e].w};
        #pragma unroll
        for (int f = 0; f < 4; f++) {
            float dr = tr4[f] - pr[e][f];
            float di = ti4[f] - pi[e][f];
            num += dr * dr + di * di;
            den += tr4[f] * tr4[f] + ti4[f] * ti4[f];
        }
    }

    #pragma unroll
    for (int off = 32; off > 0; off >>= 1) {
        num += __shfl_down(num, off, 64);
        den += __shfl_down(den, off, 64);
    }
    if (L == 0) { redN[w] = num; redD[w] = den; }
    __syncthreads();
    if (t == 0) {
        atomicAdd(&ws[0], redN[0] + redN[1] + redN[2] + redN[3]);
        atomicAdd(&ws[1], redD[0] + redD[1] + redD[2] + redD[3]);
    }
}

__global__ void fin_kernel(const float* __restrict__ ws, const int* __restrict__ bsz,
                           float* __restrict__ out) {
    if (threadIdx.x == 0 && blockIdx.x == 0) {
        float Bf = (float)bsz[0];
        float o1 = ws[2] / Bf, o2 = ws[3] / Bf;
        out[0] = ws[0] / ws[1] + 0.01f * (o1 + o2);
        out[1] = o1;
        out[2] = o2;
    }
}

extern "C" void kernel_launch(void* const* d_in, const int* in_sizes, int n_in,
                              void* d_out, int out_size, void* d_ws, size_t ws_size,
                              hipStream_t stream) {
    const float* nn = (const float*)d_in[0];
    const float* kr = (const float*)d_in[1];
    const float* ki = (const float*)d_in[2];
    const int* bsz = (const int*)d_in[3];
    float* ws = (float*)d_ws;
    float* out = (float*)d_out;
    int B = in_sizes[0] / SROW;

    int nz = GOFF + B * 2 * GS;
    hipLaunchKernelGGL(init_ws_kernel, dim3((nz + 255) / 256), dim3(256), 0, stream, ws, nz);
    hipLaunchKernelGGL(gram_kernel, dim3(B * 2 * 8), dim3(256), 0, stream, nn, ws);
    hipLaunchKernelGGL(main_kernel, dim3(E / 64, E / 64, B), dim3(256), 0, stream,
                       nn, kr, ki, ws);
    hipLaunchKernelGGL(absred_kernel, dim3(B * 2), dim3(256), 0, stream, ws);
    hipLaunchKernelGGL(fin_kernel, dim3(1), dim3(64), 0, stream, ws, bsz, out);
}